// Round 1
// baseline (260.290 us; speedup 1.0000x reference)
//
#include <hip/hip_runtime.h>

// Resample2d: backward warp of input1 (B,C,H,W) by flow input2 (B,2,H,W).
// Bilinear, border padding (clamp), align_corners semantics per reference.
// B=8 C=64 H=256 W=448, all fp32.

#define RB 8
#define RC 64
#define RH 256
#define RW 448
#define RHW (RH * RW)

__global__ __launch_bounds__(256) void resample2d_kernel(
    const float* __restrict__ img,   // (B,C,H,W)
    const float* __restrict__ flow,  // (B,2,H,W)
    float* __restrict__ out)         // (B,C,H,W)
{
    int idx = blockIdx.x * blockDim.x + threadIdx.x;   // over B*H*W
    if (idx >= RB * RHW) return;

    int x = idx % RW;
    int y = (idx / RW) % RH;
    int b = idx / RHW;

    size_t flow_base = (size_t)b * 2 * RHW + (size_t)y * RW + x;
    float fx = flow[flow_base];           // channel 0: x displacement
    float fy = flow[flow_base + RHW];     // channel 1: y displacement

    float xf = fminf(fmaxf((float)x + fx, 0.0f), (float)(RW - 1));
    float yf = fminf(fmaxf((float)y + fy, 0.0f), (float)(RH - 1));

    float x0f = floorf(xf);
    float y0f = floorf(yf);
    float wx = xf - x0f;
    float wy = yf - y0f;

    int x0 = (int)x0f;
    int y0 = (int)y0f;
    int x1 = min(x0 + 1, RW - 1);
    int y1 = min(y0 + 1, RH - 1);

    float w00 = (1.0f - wx) * (1.0f - wy);
    float w01 = wx * (1.0f - wy);
    float w10 = (1.0f - wx) * wy;
    float w11 = wx * wy;

    const float* imgb = img + (size_t)b * RC * RHW;
    float* outb = out + (size_t)b * RC * RHW;

    int o00 = y0 * RW + x0;
    int o01 = y0 * RW + x1;
    int o10 = y1 * RW + x0;
    int o11 = y1 * RW + x1;
    int oo  = y * RW + x;

    #pragma unroll 8
    for (int c = 0; c < RC; ++c) {
        const float* p = imgb + (size_t)c * RHW;
        float v = p[o00] * w00 + p[o01] * w01 + p[o10] * w10 + p[o11] * w11;
        outb[(size_t)c * RHW + oo] = v;
    }
}

extern "C" void kernel_launch(void* const* d_in, const int* in_sizes, int n_in,
                              void* d_out, int out_size, void* d_ws, size_t ws_size,
                              hipStream_t stream) {
    const float* img  = (const float*)d_in[0];
    const float* flow = (const float*)d_in[1];
    float* out = (float*)d_out;

    int total = RB * RHW;                 // one thread per (b,y,x)
    int block = 256;
    int grid = (total + block - 1) / block;   // 3584 blocks
    resample2d_kernel<<<grid, block, 0, stream>>>(img, flow, out);
}

// Round 2
// 213.781 us; speedup vs baseline: 1.2176x; 1.2176x over previous
//
#include <hip/hip_runtime.h>

// Resample2d: backward warp of input1 (B,C,H,W) by flow input2 (B,2,H,W).
// Bilinear, border padding (clamp). B=8 C=64 H=256 W=448, all fp32.
//
// Structure: one block = 448 threads = one full row width; each block
// handles ROWS=2 consecutive rows for all 64 channels. Coords/weights are
// computed once per pixel and reused across the channel loop (registers).
// Blocks are XCD-swizzled so the +-3-row gather footprint overlap between
// neighboring row-blocks is served by the same XCD's L2.

#define RB 8
#define RC 64
#define RH 256
#define RW 448
#define RHW (RH * RW)
#define ROWS 2                 // rows per block
#define NBLK (RB * RH / ROWS)  // 1024 blocks
#define NXCD 8

__global__ __launch_bounds__(RW) void resample2d_kernel(
    const float* __restrict__ img,   // (B,C,H,W)
    const float* __restrict__ flow,  // (B,2,H,W)
    float* __restrict__ out)         // (B,C,H,W)
{
    // Bijective XCD-chunked swizzle: nwg = 1024, 1024 % 8 == 0.
    int bid = blockIdx.x;
    int chunk = NBLK / NXCD;                       // 128
    int swz = (bid & (NXCD - 1)) * chunk + (bid >> 3);

    int pairs_per_batch = RH / ROWS;               // 128
    int b = swz / pairs_per_batch;
    int ybase = (swz % pairs_per_batch) * ROWS;
    int x = threadIdx.x;                           // 0..447, == full row

    int   o00[ROWS], o01[ROWS], o10[ROWS], o11[ROWS];
    float w00[ROWS], w01[ROWS], w10[ROWS], w11[ROWS];

    const size_t flow_b = (size_t)b * 2 * RHW;

    #pragma unroll
    for (int r = 0; r < ROWS; ++r) {
        int y = ybase + r;
        size_t fo = flow_b + (size_t)y * RW + x;
        float fx = flow[fo];
        float fy = flow[fo + RHW];

        float xf = fminf(fmaxf((float)x + fx, 0.0f), (float)(RW - 1));
        float yf = fminf(fmaxf((float)y + fy, 0.0f), (float)(RH - 1));

        float x0f = floorf(xf);
        float y0f = floorf(yf);
        float wx = xf - x0f;
        float wy = yf - y0f;

        int x0 = (int)x0f;
        int y0 = (int)y0f;
        int x1 = min(x0 + 1, RW - 1);
        int y1 = min(y0 + 1, RH - 1);

        w00[r] = (1.0f - wx) * (1.0f - wy);
        w01[r] = wx * (1.0f - wy);
        w10[r] = (1.0f - wx) * wy;
        w11[r] = wx * wy;

        o00[r] = y0 * RW + x0;
        o01[r] = y0 * RW + x1;
        o10[r] = y1 * RW + x0;
        o11[r] = y1 * RW + x1;
    }

    const float* imgb = img + (size_t)b * RC * RHW;
    float* outb = out + (size_t)b * RC * RHW;

    #pragma unroll 4
    for (int c = 0; c < RC; ++c) {
        const float* p = imgb + (size_t)c * RHW;
        float* q = outb + (size_t)c * RHW + (size_t)ybase * RW + x;
        #pragma unroll
        for (int r = 0; r < ROWS; ++r) {
            float v = p[o00[r]] * w00[r] + p[o01[r]] * w01[r]
                    + p[o10[r]] * w10[r] + p[o11[r]] * w11[r];
            q[(size_t)r * RW] = v;
        }
    }
}

extern "C" void kernel_launch(void* const* d_in, const int* in_sizes, int n_in,
                              void* d_out, int out_size, void* d_ws, size_t ws_size,
                              hipStream_t stream) {
    const float* img  = (const float*)d_in[0];
    const float* flow = (const float*)d_in[1];
    float* out = (float*)d_out;

    resample2d_kernel<<<NBLK, RW, 0, stream>>>(img, flow, out);
}

// Round 3
// 186.813 us; speedup vs baseline: 1.3933x; 1.1444x over previous
//
#include <hip/hip_runtime.h>

// Resample2d: backward warp of input1 (B,C,H,W) by flow input2 (B,2,H,W).
// Bilinear, border padding (clamp). B=8 C=64 H=256 W=448, all fp32.
//
// Round 3: latency-bound fix. Channel-split x4 (16 ch/block) -> 4096 blocks
// (16/CU) for queue depth; XCD-chunked swizzle keeps consecutive row-pairs
// of one (b, cgroup) on one XCD's L2; non-temporal output stores keep the
// streaming writes from evicting the gather working set.

#define RB 8
#define RC 64
#define RH 256
#define RW 448
#define RHW (RH * RW)
#define ROWS 2                    // rows per block
#define CS 4                      // channel split
#define CPB (RC / CS)             // 16 channels per block
#define PPB (RH / ROWS)           // 128 row-pairs per image
#define NBLK (RB * CS * PPB)      // 4096 blocks
#define NXCD 8

__global__ __launch_bounds__(RW) void resample2d_kernel(
    const float* __restrict__ img,   // (B,C,H,W)
    const float* __restrict__ flow,  // (B,2,H,W)
    float* __restrict__ out)         // (B,C,H,W)
{
    // Bijective XCD-chunked swizzle: NBLK = 4096, divisible by 8.
    int bid = blockIdx.x;
    const int chunk = NBLK / NXCD;                 // 512
    int id = (bid & (NXCD - 1)) * chunk + (bid >> 3);

    // id = ((b*CS + cg) * PPB + ypair): contiguous ids sweep ypairs for a
    // fixed (b,cg), so each XCD's chunk has maximal row overlap in its L2.
    int b  = id / (CS * PPB);
    int rm = id % (CS * PPB);
    int cg = rm / PPB;
    int ybase = (rm % PPB) * ROWS;
    int x = threadIdx.x;                           // 0..447 == full row

    int   o00[ROWS], o01[ROWS], o10[ROWS], o11[ROWS];
    float w00[ROWS], w01[ROWS], w10[ROWS], w11[ROWS];

    const size_t flow_b = (size_t)b * 2 * RHW;

    #pragma unroll
    for (int r = 0; r < ROWS; ++r) {
        int y = ybase + r;
        size_t fo = flow_b + (size_t)y * RW + x;
        float fx = flow[fo];
        float fy = flow[fo + RHW];

        float xf = fminf(fmaxf((float)x + fx, 0.0f), (float)(RW - 1));
        float yf = fminf(fmaxf((float)y + fy, 0.0f), (float)(RH - 1));

        float x0f = floorf(xf);
        float y0f = floorf(yf);
        float wx = xf - x0f;
        float wy = yf - y0f;

        int x0 = (int)x0f;
        int y0 = (int)y0f;
        int x1 = min(x0 + 1, RW - 1);
        int y1 = min(y0 + 1, RH - 1);

        w00[r] = (1.0f - wx) * (1.0f - wy);
        w01[r] = wx * (1.0f - wy);
        w10[r] = (1.0f - wx) * wy;
        w11[r] = wx * wy;

        o00[r] = y0 * RW + x0;
        o01[r] = y0 * RW + x1;
        o10[r] = y1 * RW + x0;
        o11[r] = y1 * RW + x1;
    }

    const float* imgb = img + ((size_t)b * RC + (size_t)cg * CPB) * RHW;
    float* outb = out + ((size_t)b * RC + (size_t)cg * CPB) * RHW
                      + (size_t)ybase * RW + x;

    #pragma unroll 8
    for (int c = 0; c < CPB; ++c) {
        const float* p = imgb + (size_t)c * RHW;
        float* q = outb + (size_t)c * RHW;
        #pragma unroll
        for (int r = 0; r < ROWS; ++r) {
            float v = p[o00[r]] * w00[r] + p[o01[r]] * w01[r]
                    + p[o10[r]] * w10[r] + p[o11[r]] * w11[r];
            __builtin_nontemporal_store(v, q + (size_t)r * RW);
        }
    }
}

extern "C" void kernel_launch(void* const* d_in, const int* in_sizes, int n_in,
                              void* d_out, int out_size, void* d_ws, size_t ws_size,
                              hipStream_t stream) {
    const float* img  = (const float*)d_in[0];
    const float* flow = (const float*)d_in[1];
    float* out = (float*)d_out;

    resample2d_kernel<<<NBLK, RW, 0, stream>>>(img, flow, out);
}

// Round 4
// 179.238 us; speedup vs baseline: 1.4522x; 1.0423x over previous
//
#include <hip/hip_runtime.h>

// Resample2d: backward warp of input1 (B,C,H,W) by flow input2 (B,2,H,W).
// Bilinear, border padding (clamp). B=8 C=64 H=256 W=448, all fp32.
//
// Round 4: occupancy/concurrency fix. 256-thread blocks (4 waves -> 8
// blocks/CU = 32/32 waves), 1 pixel/thread, 16 channels/block fully
// unrolled (64 gathers in flight/thread). 14336 blocks, XCD-chunked
// bijective swizzle keeps consecutive pixel strips of one (b,cgroup) on
// one XCD's L2. Non-temporal stores for the streaming output.

#define RB 8
#define RC 64
#define RH 256
#define RW 448
#define RHW (RH * RW)
#define THREADS 256
#define CS 4                         // channel split
#define CPB (RC / CS)                // 16 channels per block
#define SPI (RHW / THREADS)          // 448 strips per (image, cgroup)
#define NBLK (RB * CS * SPI)         // 14336 blocks
#define NXCD 8

__global__ __launch_bounds__(THREADS) void resample2d_kernel(
    const float* __restrict__ img,   // (B,C,H,W)
    const float* __restrict__ flow,  // (B,2,H,W)
    float* __restrict__ out)         // (B,C,H,W)
{
    // Bijective XCD-chunked swizzle: NBLK % NXCD == 0.
    int bid = blockIdx.x;
    const int chunk = NBLK / NXCD;                 // 1792
    int id = (bid & (NXCD - 1)) * chunk + (bid >> 3);

    // id = ((b*CS + cg) * SPI + strip): consecutive ids sweep contiguous
    // pixel strips of a fixed (b,cg) -> max row overlap within an XCD L2.
    int b  = id / (CS * SPI);
    int rm = id % (CS * SPI);
    int cg = rm / SPI;
    int pix = (rm % SPI) * THREADS + threadIdx.x;  // 0..RHW-1

    int x = pix % RW;
    int y = pix / RW;

    size_t fo = (size_t)b * 2 * RHW + pix;
    float fx = flow[fo];
    float fy = flow[fo + RHW];

    float xf = fminf(fmaxf((float)x + fx, 0.0f), (float)(RW - 1));
    float yf = fminf(fmaxf((float)y + fy, 0.0f), (float)(RH - 1));

    float x0f = floorf(xf);
    float y0f = floorf(yf);
    float wx = xf - x0f;
    float wy = yf - y0f;

    int x0 = (int)x0f;
    int y0 = (int)y0f;
    int x1 = min(x0 + 1, RW - 1);
    int y1 = min(y0 + 1, RH - 1);

    float w00 = (1.0f - wx) * (1.0f - wy);
    float w01 = wx * (1.0f - wy);
    float w10 = (1.0f - wx) * wy;
    float w11 = wx * wy;

    int o00 = y0 * RW + x0;
    int o01 = y0 * RW + x1;
    int o10 = y1 * RW + x0;
    int o11 = y1 * RW + x1;

    const float* imgb = img + ((size_t)b * RC + (size_t)cg * CPB) * RHW;
    float* outb = out + ((size_t)b * RC + (size_t)cg * CPB) * RHW + pix;

    #pragma unroll
    for (int c = 0; c < CPB; ++c) {
        const float* p = imgb + (size_t)c * RHW;
        float v = p[o00] * w00 + p[o01] * w01 + p[o10] * w10 + p[o11] * w11;
        __builtin_nontemporal_store(v, outb + (size_t)c * RHW);
    }
}

extern "C" void kernel_launch(void* const* d_in, const int* in_sizes, int n_in,
                              void* d_out, int out_size, void* d_ws, size_t ws_size,
                              hipStream_t stream) {
    const float* img  = (const float*)d_in[0];
    const float* flow = (const float*)d_in[1];
    float* out = (float*)d_out;

    resample2d_kernel<<<NBLK, THREADS, 0, stream>>>(img, flow, out);
}